// Round 1
// baseline (278.388 us; speedup 1.0000x reference)
//
#include <hip/hip_runtime.h>
#include <math.h>

#define B 16
#define N 128
#define F 128
#define CI 64
#define NEG (-9e15f)

__device__ __forceinline__ float lrelu(float x){ return x > 0.f ? x : 0.01f*x; }
__device__ __forceinline__ float sigm(float x){ return 1.f/(1.f+expf(-x)); }

// K1: h = input @ W  (per-row), then ha1 = h@a[:128], ha2 = h@a[128:], hw = h.W_fcc
__global__ __launch_bounds__(128) void k1_h(const float* __restrict__ input,
        const float* __restrict__ W, const float* __restrict__ a,
        const float* __restrict__ W_fcc,
        float* __restrict__ h, float* __restrict__ ha1, float* __restrict__ ha2,
        float* __restrict__ hw) {
    int row = blockIdx.x;           // b*N + n
    int t = threadIdx.x;
    __shared__ float x[F];
    __shared__ float hr[F];
    x[t] = input[row*F + t];
    __syncthreads();
    float acc = 0.f;
    #pragma unroll
    for (int k = 0; k < F; k++) acc += x[k] * W[k*F + t];
    h[row*F + t] = acc;
    hr[t] = acc;
    __syncthreads();
    if (t < 16) {
        float a1 = 0.f;
        #pragma unroll
        for (int f = 0; f < F; f++) a1 += hr[f] * a[f*16 + t];
        ha1[row*16 + t] = a1;
    } else if (t < 32) {
        int e = t - 16;
        float a2 = 0.f;
        #pragma unroll
        for (int f = 0; f < F; f++) a2 += hr[f] * a[(F+f)*16 + e];
        ha2[row*16 + e] = a2;
    } else if (t == 32) {
        float s = 0.f;
        #pragma unroll
        for (int f = 0; f < F; f++) s += hr[f] * W_fcc[f];
        hw[row] = s;
    }
}

// K2: attention logits + masked softmax + hn (LSTM input) + h1 = att @ h
// block = (b, chunk of 8 i-rows), 128 threads (one per j)
__global__ __launch_bounds__(128) void k2_att(
        const float* __restrict__ ha1, const float* __restrict__ ha2,
        const float* __restrict__ weight, const int* __restrict__ adj,
        const float* __restrict__ W_wf, const float* __restrict__ b_wf,
        const float* __restrict__ W_fc, const float* __restrict__ b_fc,
        const float* __restrict__ b_fcc, const float* __restrict__ hw,
        const float* __restrict__ h,
        float* __restrict__ hn, float* __restrict__ h1) {
    int b  = blockIdx.x >> 4;
    int ic = blockIdx.x & 15;
    int j = threadIdx.x;
    int lane = j & 63, wid = j >> 6;
    __shared__ float att_lds[8][N];
    __shared__ float red[2];
    float bfc = b_fc[0], bfcc = b_fcc[0];
    #pragma unroll 1
    for (int ii = 0; ii < 8; ii++) {
        int i = ic*8 + ii;
        int r1, r2;
        if (i < 64) { r1 = 2*i + (j >= 64 ? 1 : 0); r2 = r1; }
        else        { r1 = (2*j) & 127; r2 = r1 + 1; }
        const float4* p1 = (const float4*)(ha1 + (b*N + r1)*16);
        const float4* p2 = (const float4*)(ha2 + (b*N + r2)*16);
        float e16[16];
        #pragma unroll
        for (int q = 0; q < 4; q++) {
            float4 v1 = p1[q], v2 = p2[q];
            e16[q*4+0]=v1.x+v2.x; e16[q*4+1]=v1.y+v2.y;
            e16[q*4+2]=v1.z+v2.z; e16[q*4+3]=v1.w+v2.w;
        }
        const float4* wv4 = (const float4*)(weight + ((size_t)((b*N+i)*N) + j)*16);
        float wvec[16];
        #pragma unroll
        for (int q = 0; q < 4; q++) {
            float4 v = wv4[q];
            wvec[q*4]=v.x; wvec[q*4+1]=v.y; wvec[q*4+2]=v.z; wvec[q*4+3]=v.w;
        }
        float val = bfc;
        #pragma unroll
        for (int e = 0; e < 16; e++) val += lrelu(e16[e]) * W_fc[e];
        #pragma unroll
        for (int o = 0; o < 16; o++) {
            float acc = b_wf[o];
            #pragma unroll
            for (int k = 0; k < 16; k++) acc += wvec[k] * W_wf[o*16 + k];
            val += lrelu(acc) * W_fc[16 + o];
        }
        int av = adj[(b*N+i)*N + j];
        float logit = av > 0 ? val : NEG;
        // max over 128 threads
        float m = logit;
        #pragma unroll
        for (int off = 32; off > 0; off >>= 1) m = fmaxf(m, __shfl_xor(m, off));
        if (lane == 0) red[wid] = m;
        __syncthreads();
        m = fmaxf(red[0], red[1]);
        __syncthreads();
        float ex = expf(logit - m);
        float s = ex;
        #pragma unroll
        for (int off = 32; off > 0; off >>= 1) s += __shfl_xor(s, off);
        if (lane == 0) red[wid] = s;
        __syncthreads();
        s = red[0] + red[1];
        __syncthreads();
        float att = ex / s;
        att_lds[ii][j] = att;
        hn[(b*N+i)*N + j] = lrelu(att * hw[b*N+i] + bfcc);
    }
    __syncthreads();
    // h1[b, i, f] = sum_j att[b,i,j] * h[b,j,f]   (thread = f)
    float acc[8];
    #pragma unroll
    for (int ii = 0; ii < 8; ii++) acc[ii] = 0.f;
    for (int jj = 0; jj < N; jj++) {
        float hv = h[(b*N + jj)*F + j];
        #pragma unroll
        for (int ii = 0; ii < 8; ii++) acc[ii] += att_lds[ii][jj] * hv;
    }
    #pragma unroll
    for (int ii = 0; ii < 8; ii++) h1[(b*N + ic*8 + ii)*F + j] = acc[ii];
}

// K4: pre[dir] = hn @ Wih^T + bih + bhh  (rows = b*N+t, 16 rows per block)
__global__ __launch_bounds__(256) void k4_pre(
        const float* __restrict__ hn,
        const float* __restrict__ Wih_f, const float* __restrict__ bih_f, const float* __restrict__ bhh_f,
        const float* __restrict__ Wih_b, const float* __restrict__ bih_b, const float* __restrict__ bhh_b,
        float* __restrict__ pre_f, float* __restrict__ pre_b) {
    int dir = blockIdx.y;
    int g = threadIdx.x;
    const float* Wih = dir ? Wih_b : Wih_f;
    float bias = dir ? (bih_b[g] + bhh_b[g]) : (bih_f[g] + bhh_f[g]);
    float* pre = dir ? pre_b : pre_f;
    int r0 = blockIdx.x * 16;
    __shared__ float hl[16][F];
    const float4* src = (const float4*)(hn + (size_t)r0*F);
    float4* dst = (float4*)(&hl[0][0]);
    dst[g] = src[g];
    dst[g+256] = src[g+256];
    __syncthreads();
    float acc[16];
    #pragma unroll
    for (int t = 0; t < 16; t++) acc[t] = bias;
    for (int jc = 0; jc < F; jc += 16) {
        float w[16];
        const float4* wp = (const float4*)(Wih + g*F + jc);
        #pragma unroll
        for (int q = 0; q < 4; q++) {
            float4 v = wp[q];
            w[q*4]=v.x; w[q*4+1]=v.y; w[q*4+2]=v.z; w[q*4+3]=v.w;
        }
        #pragma unroll
        for (int t = 0; t < 16; t++) {
            #pragma unroll
            for (int jj = 0; jj < 16; jj++) acc[t] += hl[t][jc+jj] * w[jj];
        }
    }
    #pragma unroll
    for (int t = 0; t < 16; t++) pre[(size_t)(r0+t)*256 + g] = acc[t];
}

// K5: LSTM scan. block = (batch, dir), 256 threads (one gate each), Whh row in VGPRs
__global__ __launch_bounds__(256) void k5_lstm(
        const float* __restrict__ pre_f, const float* __restrict__ pre_b,
        const float* __restrict__ Whh_f, const float* __restrict__ Whh_b,
        float* __restrict__ hf, float* __restrict__ hb) {
    int b = blockIdx.x;
    int dir = blockIdx.y;
    const float* pre = dir ? pre_b : pre_f;
    const float* Whh = dir ? Whh_b : Whh_f;
    float* hout = dir ? hb : hf;
    int g = threadIdx.x;
    float w[CI];
    const float4* wp = (const float4*)(Whh + g*CI);
    #pragma unroll
    for (int q = 0; q < CI/4; q++) {
        float4 v = wp[q];
        w[q*4]=v.x; w[q*4+1]=v.y; w[q*4+2]=v.z; w[q*4+3]=v.w;
    }
    __shared__ float h_l[CI];
    __shared__ float gate[256];
    if (g < CI) h_l[g] = 0.f;
    float c = 0.f;
    __syncthreads();
    int tt = dir ? (N-1) : 0;
    int step = dir ? -1 : 1;
    float pnext = pre[((size_t)b*N + tt)*256 + g];
    for (int t = 0; t < N; t++) {
        float acc = pnext;
        int tn = tt + step;
        if (t < N-1) pnext = pre[((size_t)b*N + tn)*256 + g];  // prefetch under MACs
        #pragma unroll
        for (int k = 0; k < CI; k++) acc += h_l[k] * w[k];
        gate[g] = acc;
        __syncthreads();
        if (g < CI) {
            float ig = gate[g], fg = gate[CI+g], gg = gate[2*CI+g], og = gate[3*CI+g];
            c = sigm(fg)*c + sigm(ig)*tanhf(gg);
            float hv = sigm(og)*tanhf(c);
            h_l[g] = hv;
            hout[((size_t)b*N + tt)*CI + g] = hv;
        }
        __syncthreads();
        tt = tn;
    }
}

// K6: out = elu( concat(lrelu(hf), lrelu(hb), h1) @ W_out^T + b_out )
__global__ __launch_bounds__(256) void k6_out(
        const float* __restrict__ hf, const float* __restrict__ hb,
        const float* __restrict__ h1, const float* __restrict__ W_out,
        const float* __restrict__ b_out, float* __restrict__ out) {
    int r0 = blockIdx.x * 8;
    int o = threadIdx.x;
    __shared__ float rl[8][256];
    #pragma unroll
    for (int rr = 0; rr < 8; rr++) {
        int row = r0 + rr;
        float v;
        if (o < 64)       v = lrelu(hf[row*CI + o]);
        else if (o < 128) v = lrelu(hb[row*CI + (o-64)]);
        else              v = h1[row*F + (o-128)];
        rl[rr][o] = v;
    }
    __syncthreads();
    float acc[8];
    float bo = b_out[o];
    #pragma unroll
    for (int rr = 0; rr < 8; rr++) acc[rr] = bo;
    for (int dc = 0; dc < 256; dc += 16) {
        float w[16];
        const float4* wp = (const float4*)(W_out + o*256 + dc);
        #pragma unroll
        for (int q = 0; q < 4; q++) {
            float4 v = wp[q];
            w[q*4]=v.x; w[q*4+1]=v.y; w[q*4+2]=v.z; w[q*4+3]=v.w;
        }
        #pragma unroll
        for (int rr = 0; rr < 8; rr++) {
            #pragma unroll
            for (int jj = 0; jj < 16; jj++) acc[rr] += rl[rr][dc+jj] * w[jj];
        }
    }
    #pragma unroll
    for (int rr = 0; rr < 8; rr++) {
        float x = acc[rr];
        out[(size_t)(r0+rr)*256 + o] = x > 0.f ? x : (expf(x) - 1.f);
    }
}

extern "C" void kernel_launch(void* const* d_in, const int* in_sizes, int n_in,
                              void* d_out, int out_size, void* d_ws, size_t ws_size,
                              hipStream_t stream) {
    const float* input = (const float*)d_in[0];
    const int*   adj   = (const int*)  d_in[1];
    const float* weight= (const float*)d_in[2];
    const float* W     = (const float*)d_in[3];
    const float* a     = (const float*)d_in[4];
    const float* W_wf  = (const float*)d_in[5];
    const float* b_wf  = (const float*)d_in[6];
    const float* W_fc  = (const float*)d_in[7];
    const float* b_fc  = (const float*)d_in[8];
    const float* W_fcc = (const float*)d_in[9];
    const float* b_fcc = (const float*)d_in[10];
    const float* W_out = (const float*)d_in[11];
    const float* b_out = (const float*)d_in[12];
    const float* Wih_f = (const float*)d_in[13];
    const float* Whh_f = (const float*)d_in[14];
    const float* bih_f = (const float*)d_in[15];
    const float* bhh_f = (const float*)d_in[16];
    const float* Wih_b = (const float*)d_in[17];
    const float* Whh_b = (const float*)d_in[18];
    const float* bih_b = (const float*)d_in[19];
    const float* bhh_b = (const float*)d_in[20];

    float* ws = (float*)d_ws;
    float* h    = ws;             // 262144
    float* ha1  = ws + 262144;    // 32768
    float* ha2  = ws + 294912;    // 32768
    float* hw   = ws + 327680;    // 2048
    float* hn   = ws + 329728;    // 262144
    float* h1   = ws + 591872;    // 262144
    float* pre_f= ws + 854016;    // 524288
    float* pre_b= ws + 1378304;   // 524288
    float* hf   = ws + 1902592;   // 131072
    float* hb   = ws + 2033664;   // 131072

    k1_h<<<B*N, 128, 0, stream>>>(input, W, a, W_fcc, h, ha1, ha2, hw);
    k2_att<<<B*16, 128, 0, stream>>>(ha1, ha2, weight, adj, W_wf, b_wf, W_fc,
                                     b_fc, b_fcc, hw, h, hn, h1);
    k4_pre<<<dim3(128, 2), 256, 0, stream>>>(hn, Wih_f, bih_f, bhh_f,
                                             Wih_b, bih_b, bhh_b, pre_f, pre_b);
    k5_lstm<<<dim3(B, 2), 256, 0, stream>>>(pre_f, pre_b, Whh_f, Whh_b, hf, hb);
    k6_out<<<256, 256, 0, stream>>>(hf, hb, h1, W_out, b_out, (float*)d_out);
}

// Round 3
// 229.686 us; speedup vs baseline: 1.2120x; 1.2120x over previous
//
#include <hip/hip_runtime.h>
#include <math.h>

#define B 16
#define N 128
#define F 128
#define CI 64
#define NEG (-9e15f)

__device__ __forceinline__ float lrelu(float x){ return x > 0.f ? x : 0.01f*x; }
__device__ __forceinline__ float fastrcp(float x){ return __builtin_amdgcn_rcpf(x); }
__device__ __forceinline__ float sigm(float x){ return fastrcp(1.f + __expf(-x)); }
// tanh(x) = 1 - 2/(exp(2x)+1); saturates correctly at +/-inf
__device__ __forceinline__ float tanh_f(float x){ return 1.f - 2.f*fastrcp(__expf(2.f*x) + 1.f); }
__device__ __forceinline__ float rdlane(float v, int l) {
    return __int_as_float(__builtin_amdgcn_readlane(__float_as_int(v), l));
}

// K1: h = input @ W  (per-row), then ha1 = h@a[:128], ha2 = h@a[128:], hw = h.W_fcc
__global__ __launch_bounds__(128) void k1_h(const float* __restrict__ input,
        const float* __restrict__ W, const float* __restrict__ a,
        const float* __restrict__ W_fcc,
        float* __restrict__ h, float* __restrict__ ha1, float* __restrict__ ha2,
        float* __restrict__ hw) {
    int row = blockIdx.x;           // b*N + n
    int t = threadIdx.x;
    __shared__ float x[F];
    __shared__ float hr[F];
    x[t] = input[row*F + t];
    __syncthreads();
    float acc = 0.f;
    #pragma unroll
    for (int k = 0; k < F; k++) acc += x[k] * W[k*F + t];
    h[row*F + t] = acc;
    hr[t] = acc;
    __syncthreads();
    if (t < 16) {
        float a1 = 0.f;
        #pragma unroll
        for (int f = 0; f < F; f++) a1 += hr[f] * a[f*16 + t];
        ha1[row*16 + t] = a1;
    } else if (t < 32) {
        int e = t - 16;
        float a2 = 0.f;
        #pragma unroll
        for (int f = 0; f < F; f++) a2 += hr[f] * a[(F+f)*16 + e];
        ha2[row*16 + e] = a2;
    } else if (t == 32) {
        float s = 0.f;
        #pragma unroll
        for (int f = 0; f < F; f++) s += hr[f] * W_fcc[f];
        hw[row] = s;
    }
}

// K2: attention logits + masked softmax + hn (LSTM input) + h1 = att @ h
// block = (b, chunk of 2 i-rows), 128 threads (one per j)
__global__ __launch_bounds__(128) void k2_att(
        const float* __restrict__ ha1, const float* __restrict__ ha2,
        const float* __restrict__ weight, const int* __restrict__ adj,
        const float* __restrict__ W_wf, const float* __restrict__ b_wf,
        const float* __restrict__ W_fc, const float* __restrict__ b_fc,
        const float* __restrict__ b_fcc, const float* __restrict__ hw,
        const float* __restrict__ h,
        float* __restrict__ hn, float* __restrict__ h1) {
    int b  = blockIdx.x >> 6;
    int ic = blockIdx.x & 63;
    int j = threadIdx.x;
    int lane = j & 63, wid = j >> 6;
    __shared__ float att_lds[2][N];
    __shared__ float red[2];
    float bfc = b_fc[0], bfcc = b_fcc[0];
    #pragma unroll 1
    for (int ii = 0; ii < 2; ii++) {
        int i = ic*2 + ii;
        int r1, r2;
        if (i < 64) { r1 = 2*i + (j >= 64 ? 1 : 0); r2 = r1; }
        else        { r1 = (2*j) & 127; r2 = r1 + 1; }
        const float4* p1 = (const float4*)(ha1 + (b*N + r1)*16);
        const float4* p2 = (const float4*)(ha2 + (b*N + r2)*16);
        float e16[16];
        #pragma unroll
        for (int q = 0; q < 4; q++) {
            float4 v1 = p1[q], v2 = p2[q];
            e16[q*4+0]=v1.x+v2.x; e16[q*4+1]=v1.y+v2.y;
            e16[q*4+2]=v1.z+v2.z; e16[q*4+3]=v1.w+v2.w;
        }
        const float4* wv4 = (const float4*)(weight + ((size_t)((b*N+i)*N) + j)*16);
        float wvec[16];
        #pragma unroll
        for (int q = 0; q < 4; q++) {
            float4 v = wv4[q];
            wvec[q*4]=v.x; wvec[q*4+1]=v.y; wvec[q*4+2]=v.z; wvec[q*4+3]=v.w;
        }
        float val = bfc;
        #pragma unroll
        for (int e = 0; e < 16; e++) val += lrelu(e16[e]) * W_fc[e];
        #pragma unroll
        for (int o = 0; o < 16; o++) {
            float acc = b_wf[o];
            #pragma unroll
            for (int k = 0; k < 16; k++) acc += wvec[k] * W_wf[o*16 + k];
            val += lrelu(acc) * W_fc[16 + o];
        }
        int av = adj[(b*N+i)*N + j];
        float logit = av > 0 ? val : NEG;
        // max over 128 threads
        float m = logit;
        #pragma unroll
        for (int off = 32; off > 0; off >>= 1) m = fmaxf(m, __shfl_xor(m, off));
        if (lane == 0) red[wid] = m;
        __syncthreads();
        m = fmaxf(red[0], red[1]);
        __syncthreads();
        float ex = __expf(logit - m);
        float s = ex;
        #pragma unroll
        for (int off = 32; off > 0; off >>= 1) s += __shfl_xor(s, off);
        if (lane == 0) red[wid] = s;
        __syncthreads();
        s = red[0] + red[1];
        __syncthreads();
        float att = ex / s;
        att_lds[ii][j] = att;
        hn[(b*N+i)*N + j] = lrelu(att * hw[b*N+i] + bfcc);
    }
    __syncthreads();
    // h1[b, i, f] = sum_j att[b,i,j] * h[b,j,f]   (thread = f)
    float acc[2];
    #pragma unroll
    for (int ii = 0; ii < 2; ii++) acc[ii] = 0.f;
    for (int jj = 0; jj < N; jj++) {
        float hv = h[(b*N + jj)*F + j];
        #pragma unroll
        for (int ii = 0; ii < 2; ii++) acc[ii] += att_lds[ii][jj] * hv;
    }
    #pragma unroll
    for (int ii = 0; ii < 2; ii++) h1[(b*N + ic*2 + ii)*F + j] = acc[ii];
}

// K4: pre[dir] = hn @ Wih^T + bih + bhh  (rows = b*N+t, 16 rows per block)
__global__ __launch_bounds__(256) void k4_pre(
        const float* __restrict__ hn,
        const float* __restrict__ Wih_f, const float* __restrict__ bih_f, const float* __restrict__ bhh_f,
        const float* __restrict__ Wih_b, const float* __restrict__ bih_b, const float* __restrict__ bhh_b,
        float* __restrict__ pre_f, float* __restrict__ pre_b) {
    int dir = blockIdx.y;
    int g = threadIdx.x;
    const float* Wih = dir ? Wih_b : Wih_f;
    float bias = dir ? (bih_b[g] + bhh_b[g]) : (bih_f[g] + bhh_f[g]);
    float* pre = dir ? pre_b : pre_f;
    int r0 = blockIdx.x * 16;
    __shared__ float hl[16][F];
    const float4* src = (const float4*)(hn + (size_t)r0*F);
    float4* dst = (float4*)(&hl[0][0]);
    dst[g] = src[g];
    dst[g+256] = src[g+256];
    __syncthreads();
    float acc[16];
    #pragma unroll
    for (int t = 0; t < 16; t++) acc[t] = bias;
    for (int jc = 0; jc < F; jc += 16) {
        float w[16];
        const float4* wp = (const float4*)(Wih + g*F + jc);
        #pragma unroll
        for (int q = 0; q < 4; q++) {
            float4 v = wp[q];
            w[q*4]=v.x; w[q*4+1]=v.y; w[q*4+2]=v.z; w[q*4+3]=v.w;
        }
        #pragma unroll
        for (int t = 0; t < 16; t++) {
            #pragma unroll
            for (int jj = 0; jj < 16; jj++) acc[t] += hl[t][jc+jj] * w[jj];
        }
    }
    #pragma unroll
    for (int t = 0; t < 16; t++) pre[(size_t)(r0+t)*256 + g] = acc[t];
}

// K5: LSTM scan. block = (batch, dir), 256 threads (one gate each).
// h broadcast via v_readlane (register), gates via double-buffered LDS,
// nonlinearity computed redundantly by all 4 waves -> ONE barrier per step.
__global__ __launch_bounds__(256) void k5_lstm(
        const float* __restrict__ pre_f, const float* __restrict__ pre_b,
        const float* __restrict__ Whh_f, const float* __restrict__ Whh_b,
        float* __restrict__ hf, float* __restrict__ hb) {
    int b = blockIdx.x;
    int dir = blockIdx.y;
    const float* pre = dir ? pre_b : pre_f;
    const float* Whh = dir ? Whh_b : Whh_f;
    float* hout = dir ? hb : hf;
    int g = threadIdx.x;
    int lane = g & 63;
    float w[CI];
    const float4* wp = (const float4*)(Whh + g*CI);
    #pragma unroll
    for (int q = 0; q < CI/4; q++) {
        float4 v = wp[q];
        w[q*4]=v.x; w[q*4+1]=v.y; w[q*4+2]=v.z; w[q*4+3]=v.w;
    }
    __shared__ float gate[2][256];
    float hreg = 0.f;   // h[lane], replicated in every wave
    float c = 0.f;      // c[lane], replicated in every wave
    int tt = dir ? (N-1) : 0;
    int step = dir ? -1 : 1;
    float pnext = pre[((size_t)b*N + tt)*256 + g];
    int buf = 0;
    for (int t = 0; t < N; t++) {
        float a0 = pnext, a1 = 0.f, a2 = 0.f, a3 = 0.f;
        if (t < N-1) pnext = pre[((size_t)b*N + tt + step)*256 + g];  // prefetch
        #pragma unroll
        for (int k = 0; k < CI; k += 4) {
            a0 += rdlane(hreg, k+0) * w[k+0];
            a1 += rdlane(hreg, k+1) * w[k+1];
            a2 += rdlane(hreg, k+2) * w[k+2];
            a3 += rdlane(hreg, k+3) * w[k+3];
        }
        gate[buf][g] = (a0 + a1) + (a2 + a3);
        __syncthreads();
        float ig = gate[buf][lane];
        float fg = gate[buf][CI + lane];
        float gg = gate[buf][2*CI + lane];
        float og = gate[buf][3*CI + lane];
        c = sigm(fg)*c + sigm(ig)*tanh_f(gg);
        float hv = sigm(og)*tanh_f(c);
        hreg = hv;
        if (g < CI) hout[((size_t)b*N + tt)*CI + lane] = hv;
        buf ^= 1;
        tt += step;
    }
}

// K6: out = elu( concat(lrelu(hf), lrelu(hb), h1) @ W_out^T + b_out )
__global__ __launch_bounds__(256) void k6_out(
        const float* __restrict__ hf, const float* __restrict__ hb,
        const float* __restrict__ h1, const float* __restrict__ W_out,
        const float* __restrict__ b_out, float* __restrict__ out) {
    int r0 = blockIdx.x * 8;
    int o = threadIdx.x;
    __shared__ float rl[8][256];
    #pragma unroll
    for (int rr = 0; rr < 8; rr++) {
        int row = r0 + rr;
        float v;
        if (o < 64)       v = lrelu(hf[row*CI + o]);
        else if (o < 128) v = lrelu(hb[row*CI + (o-64)]);
        else              v = h1[row*F + (o-128)];
        rl[rr][o] = v;
    }
    __syncthreads();
    float acc[8];
    float bo = b_out[o];
    #pragma unroll
    for (int rr = 0; rr < 8; rr++) acc[rr] = bo;
    for (int dc = 0; dc < 256; dc += 16) {
        float w[16];
        const float4* wp = (const float4*)(W_out + o*256 + dc);
        #pragma unroll
        for (int q = 0; q < 4; q++) {
            float4 v = wp[q];
            w[q*4]=v.x; w[q*4+1]=v.y; w[q*4+2]=v.z; w[q*4+3]=v.w;
        }
        #pragma unroll
        for (int rr = 0; rr < 8; rr++) {
            #pragma unroll
            for (int jj = 0; jj < 16; jj++) acc[rr] += rl[rr][dc+jj] * w[jj];
        }
    }
    #pragma unroll
    for (int rr = 0; rr < 8; rr++) {
        float x = acc[rr];
        out[(size_t)(r0+rr)*256 + o] = x > 0.f ? x : (__expf(x) - 1.f);
    }
}

extern "C" void kernel_launch(void* const* d_in, const int* in_sizes, int n_in,
                              void* d_out, int out_size, void* d_ws, size_t ws_size,
                              hipStream_t stream) {
    const float* input = (const float*)d_in[0];
    const int*   adj   = (const int*)  d_in[1];
    const float* weight= (const float*)d_in[2];
    const float* W     = (const float*)d_in[3];
    const float* a     = (const float*)d_in[4];
    const float* W_wf  = (const float*)d_in[5];
    const float* b_wf  = (const float*)d_in[6];
    const float* W_fc  = (const float*)d_in[7];
    const float* b_fc  = (const float*)d_in[8];
    const float* W_fcc = (const float*)d_in[9];
    const float* b_fcc = (const float*)d_in[10];
    const float* W_out = (const float*)d_in[11];
    const float* b_out = (const float*)d_in[12];
    const float* Wih_f = (const float*)d_in[13];
    const float* Whh_f = (const float*)d_in[14];
    const float* bih_f = (const float*)d_in[15];
    const float* bhh_f = (const float*)d_in[16];
    const float* Wih_b = (const float*)d_in[17];
    const float* Whh_b = (const float*)d_in[18];
    const float* bih_b = (const float*)d_in[19];
    const float* bhh_b = (const float*)d_in[20];

    float* ws = (float*)d_ws;
    float* h    = ws;             // 262144
    float* ha1  = ws + 262144;    // 32768
    float* ha2  = ws + 294912;    // 32768
    float* hw   = ws + 327680;    // 2048
    float* hn   = ws + 329728;    // 262144
    float* h1   = ws + 591872;    // 262144
    float* pre_f= ws + 854016;    // 524288
    float* pre_b= ws + 1378304;   // 524288
    float* hf   = ws + 1902592;   // 131072
    float* hb   = ws + 2033664;   // 131072

    k1_h<<<B*N, 128, 0, stream>>>(input, W, a, W_fcc, h, ha1, ha2, hw);
    k2_att<<<B*64, 128, 0, stream>>>(ha1, ha2, weight, adj, W_wf, b_wf, W_fc,
                                     b_fc, b_fcc, hw, h, hn, h1);
    k4_pre<<<dim3(128, 2), 256, 0, stream>>>(hn, Wih_f, bih_f, bhh_f,
                                             Wih_b, bih_b, bhh_b, pre_f, pre_b);
    k5_lstm<<<dim3(B, 2), 256, 0, stream>>>(pre_f, pre_b, Whh_f, Whh_b, hf, hb);
    k6_out<<<256, 256, 0, stream>>>(hf, hb, h1, W_out, b_out, (float*)d_out);
}

// Round 5
// 224.994 us; speedup vs baseline: 1.2373x; 1.0209x over previous
//
#include <hip/hip_runtime.h>
#include <math.h>

#define B 16
#define N 128
#define F 128
#define CI 64
#define NEG (-9e15f)

__device__ __forceinline__ float lrelu(float x){ return x > 0.f ? x : 0.01f*x; }
__device__ __forceinline__ float fastrcp(float x){ return __builtin_amdgcn_rcpf(x); }
__device__ __forceinline__ float sigm(float x){ return fastrcp(1.f + __expf(-x)); }
// tanh(x) = 1 - 2/(exp(2x)+1); saturates correctly at +/-inf
__device__ __forceinline__ float tanh_f(float x){ return 1.f - 2.f*fastrcp(__expf(2.f*x) + 1.f); }
__device__ __forceinline__ float rdlane(float v, int l) {
    return __int_as_float(__builtin_amdgcn_readlane(__float_as_int(v), l));
}

// K1: h = input @ W  (per-row), then ha1 = h@a[:128], ha2 = h@a[128:], hw = h.W_fcc
__global__ __launch_bounds__(128) void k1_h(const float* __restrict__ input,
        const float* __restrict__ W, const float* __restrict__ a,
        const float* __restrict__ W_fcc,
        float* __restrict__ h, float* __restrict__ ha1, float* __restrict__ ha2,
        float* __restrict__ hw) {
    int row = blockIdx.x;           // b*N + n
    int t = threadIdx.x;
    __shared__ float x[F];
    __shared__ float hr[F];
    x[t] = input[row*F + t];
    __syncthreads();
    float acc = 0.f;
    #pragma unroll
    for (int k = 0; k < F; k++) acc += x[k] * W[k*F + t];
    h[row*F + t] = acc;
    hr[t] = acc;
    __syncthreads();
    if (t < 16) {
        float a1 = 0.f;
        #pragma unroll
        for (int f = 0; f < F; f++) a1 += hr[f] * a[f*16 + t];
        ha1[row*16 + t] = a1;
    } else if (t < 32) {
        int e = t - 16;
        float a2 = 0.f;
        #pragma unroll
        for (int f = 0; f < F; f++) a2 += hr[f] * a[(F+f)*16 + e];
        ha2[row*16 + e] = a2;
    } else if (t == 32) {
        float s = 0.f;
        #pragma unroll
        for (int f = 0; f < F; f++) s += hr[f] * W_fcc[f];
        hw[row] = s;
    }
}

// K2: attention logits + masked softmax + hn (LSTM input) + h1 = att @ h
// block = (b, chunk of 2 i-rows), 128 threads (one per j)
__global__ __launch_bounds__(128) void k2_att(
        const float* __restrict__ ha1, const float* __restrict__ ha2,
        const float* __restrict__ weight, const int* __restrict__ adj,
        const float* __restrict__ W_wf, const float* __restrict__ b_wf,
        const float* __restrict__ W_fc, const float* __restrict__ b_fc,
        const float* __restrict__ b_fcc, const float* __restrict__ hw,
        const float* __restrict__ h,
        float* __restrict__ hn, float* __restrict__ h1) {
    int b  = blockIdx.x >> 6;
    int ic = blockIdx.x & 63;
    int j = threadIdx.x;
    int lane = j & 63, wid = j >> 6;
    __shared__ float att_lds[2][N];
    __shared__ float red[2];
    float bfc = b_fc[0], bfcc = b_fcc[0];
    #pragma unroll 1
    for (int ii = 0; ii < 2; ii++) {
        int i = ic*2 + ii;
        int r1, r2;
        if (i < 64) { r1 = 2*i + (j >= 64 ? 1 : 0); r2 = r1; }
        else        { r1 = (2*j) & 127; r2 = r1 + 1; }
        const float4* p1 = (const float4*)(ha1 + (b*N + r1)*16);
        const float4* p2 = (const float4*)(ha2 + (b*N + r2)*16);
        float e16[16];
        #pragma unroll
        for (int q = 0; q < 4; q++) {
            float4 v1 = p1[q], v2 = p2[q];
            e16[q*4+0]=v1.x+v2.x; e16[q*4+1]=v1.y+v2.y;
            e16[q*4+2]=v1.z+v2.z; e16[q*4+3]=v1.w+v2.w;
        }
        const float4* wv4 = (const float4*)(weight + ((size_t)((b*N+i)*N) + j)*16);
        float wvec[16];
        #pragma unroll
        for (int q = 0; q < 4; q++) {
            float4 v = wv4[q];
            wvec[q*4]=v.x; wvec[q*4+1]=v.y; wvec[q*4+2]=v.z; wvec[q*4+3]=v.w;
        }
        float val = bfc;
        #pragma unroll
        for (int e = 0; e < 16; e++) val += lrelu(e16[e]) * W_fc[e];
        #pragma unroll
        for (int o = 0; o < 16; o++) {
            float acc = b_wf[o];
            #pragma unroll
            for (int k = 0; k < 16; k++) acc += wvec[k] * W_wf[o*16 + k];
            val += lrelu(acc) * W_fc[16 + o];
        }
        int av = adj[(b*N+i)*N + j];
        float logit = av > 0 ? val : NEG;
        // max over 128 threads
        float m = logit;
        #pragma unroll
        for (int off = 32; off > 0; off >>= 1) m = fmaxf(m, __shfl_xor(m, off));
        if (lane == 0) red[wid] = m;
        __syncthreads();
        m = fmaxf(red[0], red[1]);
        __syncthreads();
        float ex = __expf(logit - m);
        float s = ex;
        #pragma unroll
        for (int off = 32; off > 0; off >>= 1) s += __shfl_xor(s, off);
        if (lane == 0) red[wid] = s;
        __syncthreads();
        s = red[0] + red[1];
        __syncthreads();
        float att = ex / s;
        att_lds[ii][j] = att;
        hn[(b*N+i)*N + j] = lrelu(att * hw[b*N+i] + bfcc);
    }
    __syncthreads();
    // h1[b, i, f] = sum_j att[b,i,j] * h[b,j,f]   (thread = f)
    float acc[2];
    #pragma unroll
    for (int ii = 0; ii < 2; ii++) acc[ii] = 0.f;
    for (int jj = 0; jj < N; jj++) {
        float hv = h[(b*N + jj)*F + j];
        #pragma unroll
        for (int ii = 0; ii < 2; ii++) acc[ii] += att_lds[ii][jj] * hv;
    }
    #pragma unroll
    for (int ii = 0; ii < 2; ii++) h1[(b*N + ic*2 + ii)*F + j] = acc[ii];
}

// K4: pre[dir] = hn @ Wih^T + bih + bhh  (rows = b*N+t, 16 rows per block)
__global__ __launch_bounds__(256) void k4_pre(
        const float* __restrict__ hn,
        const float* __restrict__ Wih_f, const float* __restrict__ bih_f, const float* __restrict__ bhh_f,
        const float* __restrict__ Wih_b, const float* __restrict__ bih_b, const float* __restrict__ bhh_b,
        float* __restrict__ pre_f, float* __restrict__ pre_b) {
    int dir = blockIdx.y;
    int g = threadIdx.x;
    const float* Wih = dir ? Wih_b : Wih_f;
    float bias = dir ? (bih_b[g] + bhh_b[g]) : (bih_f[g] + bhh_f[g]);
    float* pre = dir ? pre_b : pre_f;
    int r0 = blockIdx.x * 16;
    __shared__ float hl[16][F];
    const float4* src = (const float4*)(hn + (size_t)r0*F);
    float4* dst = (float4*)(&hl[0][0]);
    dst[g] = src[g];
    dst[g+256] = src[g+256];
    __syncthreads();
    float acc[16];
    #pragma unroll
    for (int t = 0; t < 16; t++) acc[t] = bias;
    for (int jc = 0; jc < F; jc += 16) {
        float w[16];
        const float4* wp = (const float4*)(Wih + g*F + jc);
        #pragma unroll
        for (int q = 0; q < 4; q++) {
            float4 v = wp[q];
            w[q*4]=v.x; w[q*4+1]=v.y; w[q*4+2]=v.z; w[q*4+3]=v.w;
        }
        #pragma unroll
        for (int t = 0; t < 16; t++) {
            #pragma unroll
            for (int jj = 0; jj < 16; jj++) acc[t] += hl[t][jc+jj] * w[jj];
        }
    }
    #pragma unroll
    for (int t = 0; t < 16; t++) pre[(size_t)(r0+t)*256 + g] = acc[t];
}

// K5: LSTM scan. block = (batch, dir), 256 threads (one gate each).
// No global vmem inside the barriered loop: h staged in LDS, bulk-stored at end.
// Raw s_barrier (lgkmcnt-only drain) instead of __syncthreads (which drains vmcnt
// and would serialize on the prefetch load / any store retire).
__global__ __launch_bounds__(256, 1) void k5_lstm(
        const float* __restrict__ pre_f, const float* __restrict__ pre_b,
        const float* __restrict__ Whh_f, const float* __restrict__ Whh_b,
        float* __restrict__ hf, float* __restrict__ hb) {
    int b = blockIdx.x;
    int dir = blockIdx.y;
    const float* pre = dir ? pre_b : pre_f;
    const float* Whh = dir ? Whh_b : Whh_f;
    float* hout = dir ? hb : hf;
    int g = threadIdx.x;
    int lane = g & 63;
    int gid = g >> 6;
    float w[CI];
    const float4* wp = (const float4*)(Whh + g*CI);
    #pragma unroll
    for (int q = 0; q < CI/4; q++) {
        float4 v = wp[q];
        w[q*4]=v.x; w[q*4+1]=v.y; w[q*4+2]=v.z; w[q*4+3]=v.w;
    }
    __shared__ float gate_t[2][CI][4];   // [buf][element][gate-id], read as float4
    __shared__ float hlds[N][CI];        // staged h outputs, bulk-stored at end
    float hreg = 0.f;   // h[lane], replicated in every wave
    float c = 0.f;      // c[lane], replicated in every wave
    int tt = dir ? (N-1) : 0;
    int step = dir ? -1 : 1;
    float pnext = pre[((size_t)b*N + tt)*256 + g];
    int buf = 0;
    for (int t = 0; t < N; t++) {
        float a0 = pnext, a1 = 0.f, a2 = 0.f, a3 = 0.f;
        if (t < N-1) pnext = pre[((size_t)b*N + tt + step)*256 + g];  // prefetch
        #pragma unroll
        for (int k = 0; k < CI; k += 4) {
            a0 += rdlane(hreg, k+0) * w[k+0];
            a1 += rdlane(hreg, k+1) * w[k+1];
            a2 += rdlane(hreg, k+2) * w[k+2];
            a3 += rdlane(hreg, k+3) * w[k+3];
        }
        gate_t[buf][lane][gid] = (a0 + a1) + (a2 + a3);
        // LDS-only drain + raw barrier: vmcnt (prefetch load) stays in flight.
        asm volatile("s_waitcnt lgkmcnt(0)" ::: "memory");
        __builtin_amdgcn_s_barrier();
        __builtin_amdgcn_sched_barrier(0);
        float4 gv = *(const float4*)gate_t[buf][lane];  // (i,f,g,o) one ds_read_b128
        c = sigm(gv.y)*c + sigm(gv.x)*tanh_f(gv.z);
        float hv = sigm(gv.w)*tanh_f(c);
        hreg = hv;
        if (g < CI) hlds[tt][lane] = hv;   // LDS stage, not global
        buf ^= 1;
        tt += step;
    }
    __syncthreads();   // full drain once; hlds visible to all
    // bulk copy 128*64 floats -> global, coalesced float4
    const float4* src = (const float4*)&hlds[0][0];
    float4* dst = (float4*)(hout + (size_t)b*N*CI);
    #pragma unroll
    for (int j = 0; j < 8; j++) dst[g + j*256] = src[g + j*256];
}

// K6: out = elu( concat(lrelu(hf), lrelu(hb), h1) @ W_out^T + b_out )
__global__ __launch_bounds__(256) void k6_out(
        const float* __restrict__ hf, const float* __restrict__ hb,
        const float* __restrict__ h1, const float* __restrict__ W_out,
        const float* __restrict__ b_out, float* __restrict__ out) {
    int r0 = blockIdx.x * 8;
    int o = threadIdx.x;
    __shared__ float rl[8][256];
    #pragma unroll
    for (int rr = 0; rr < 8; rr++) {
        int row = r0 + rr;
        float v;
        if (o < 64)       v = lrelu(hf[row*CI + o]);
        else if (o < 128) v = lrelu(hb[row*CI + (o-64)]);
        else              v = h1[row*F + (o-128)];
        rl[rr][o] = v;
    }
    __syncthreads();
    float acc[8];
    float bo = b_out[o];
    #pragma unroll
    for (int rr = 0; rr < 8; rr++) acc[rr] = bo;
    for (int dc = 0; dc < 256; dc += 16) {
        float w[16];
        const float4* wp = (const float4*)(W_out + o*256 + dc);
        #pragma unroll
        for (int q = 0; q < 4; q++) {
            float4 v = wp[q];
            w[q*4]=v.x; w[q*4+1]=v.y; w[q*4+2]=v.z; w[q*4+3]=v.w;
        }
        #pragma unroll
        for (int rr = 0; rr < 8; rr++) {
            #pragma unroll
            for (int jj = 0; jj < 16; jj++) acc[rr] += rl[rr][dc+jj] * w[jj];
        }
    }
    #pragma unroll
    for (int rr = 0; rr < 8; rr++) {
        float x = acc[rr];
        out[(size_t)(r0+rr)*256 + o] = x > 0.f ? x : (__expf(x) - 1.f);
    }
}

extern "C" void kernel_launch(void* const* d_in, const int* in_sizes, int n_in,
                              void* d_out, int out_size, void* d_ws, size_t ws_size,
                              hipStream_t stream) {
    const float* input = (const float*)d_in[0];
    const int*   adj   = (const int*)  d_in[1];
    const float* weight= (const float*)d_in[2];
    const float* W     = (const float*)d_in[3];
    const float* a     = (const float*)d_in[4];
    const float* W_wf  = (const float*)d_in[5];
    const float* b_wf  = (const float*)d_in[6];
    const float* W_fc  = (const float*)d_in[7];
    const float* b_fc  = (const float*)d_in[8];
    const float* W_fcc = (const float*)d_in[9];
    const float* b_fcc = (const float*)d_in[10];
    const float* W_out = (const float*)d_in[11];
    const float* b_out = (const float*)d_in[12];
    const float* Wih_f = (const float*)d_in[13];
    const float* Whh_f = (const float*)d_in[14];
    const float* bih_f = (const float*)d_in[15];
    const float* bhh_f = (const float*)d_in[16];
    const float* Wih_b = (const float*)d_in[17];
    const float* Whh_b = (const float*)d_in[18];
    const float* bih_b = (const float*)d_in[19];
    const float* bhh_b = (const float*)d_in[20];

    float* ws = (float*)d_ws;
    float* h    = ws;             // 262144
    float* ha1  = ws + 262144;    // 32768
    float* ha2  = ws + 294912;    // 32768
    float* hw   = ws + 327680;    // 2048
    float* hn   = ws + 329728;    // 262144
    float* h1   = ws + 591872;    // 262144
    float* pre_f= ws + 854016;    // 524288
    float* pre_b= ws + 1378304;   // 524288
    float* hf   = ws + 1902592;   // 131072
    float* hb   = ws + 2033664;   // 131072

    k1_h<<<B*N, 128, 0, stream>>>(input, W, a, W_fcc, h, ha1, ha2, hw);
    k2_att<<<B*64, 128, 0, stream>>>(ha1, ha2, weight, adj, W_wf, b_wf, W_fc,
                                     b_fc, b_fcc, hw, h, hn, h1);
    k4_pre<<<dim3(128, 2), 256, 0, stream>>>(hn, Wih_f, bih_f, bhh_f,
                                             Wih_b, bih_b, bhh_b, pre_f, pre_b);
    k5_lstm<<<dim3(B, 2), 256, 0, stream>>>(pre_f, pre_b, Whh_f, Whh_b, hf, hb);
    k6_out<<<256, 256, 0, stream>>>(hf, hb, h1, W_out, b_out, (float*)d_out);
}